// Round 1
// baseline (1695.338 us; speedup 1.0000x reference)
//
#include <hip/hip_runtime.h>
#include <cmath>

// ============================================================================
// Stage 1: fused conv1 + relu + maxpool2x2 + conv2 + relu + spatial-sum
// One block per (batch, 32x32 tile of the 128x128 pooled image).
// Writes per-tile partial channel sums -> part[64][16][32] (deterministic,
// no atomics).
// ============================================================================
__global__ __launch_bounds__(256) void k_conv(
    const float* __restrict__ mask, const float* __restrict__ w1,
    const float* __restrict__ b1, const float* __restrict__ w2,
    const float* __restrict__ b2, float* __restrict__ part)
{
  __shared__ float s_p1[16][34 * 36];  // conv1+pool tile with halo, pad 36
  __shared__ float s_w1[144];
  __shared__ float s_b1[16];
  __shared__ float s_w2[4608];
  __shared__ float s_b2[32];

  const int tid = threadIdx.x;
  const int b = blockIdx.x >> 4;
  const int tile = blockIdx.x & 15;
  const int py0 = (tile >> 2) * 32, px0 = (tile & 3) * 32;
  const float* mb = mask + (size_t)b * 65536;

  for (int i = tid; i < 144; i += 256) s_w1[i] = w1[i];
  for (int i = tid; i < 4608; i += 256) s_w2[i] = w2[i];
  if (tid < 16) s_b1[tid] = b1[tid];
  if (tid < 32) s_b2[tid] = b2[tid];
  __syncthreads();

  // Phase B: conv1 + relu + 2x2 maxpool into s_p1 (34x34 incl. halo).
  // relu folded into max by initializing the max with 0.
  for (int idx = tid; idx < 34 * 34; idx += 256) {
    int ly = idx / 34, lx = idx % 34;
    int py = py0 - 1 + ly, px = px0 - 1 + lx;
    if (py < 0 || py >= 128 || px < 0 || px >= 128) {
      for (int o = 0; o < 16; o++) s_p1[o][ly * 36 + lx] = 0.f;
    } else {
      float patch[4][4];
      int gy0 = 2 * py - 1, gx0 = 2 * px - 1;
#pragma unroll
      for (int i = 0; i < 4; i++) {
        int gy = gy0 + i;
        bool yok = (gy >= 0 && gy < 256);
#pragma unroll
        for (int j = 0; j < 4; j++) {
          int gx = gx0 + j;
          patch[i][j] = (yok && gx >= 0 && gx < 256) ? mb[gy * 256 + gx] : 0.f;
        }
      }
      for (int o = 0; o < 16; o++) {
        float m = 0.f;
#pragma unroll
        for (int dy = 0; dy < 2; dy++)
#pragma unroll
          for (int dx = 0; dx < 2; dx++) {
            float v = s_b1[o];
#pragma unroll
            for (int ky = 0; ky < 3; ky++)
#pragma unroll
              for (int kx = 0; kx < 3; kx++)
                v = fmaf(patch[dy + ky][dx + kx], s_w1[o * 9 + ky * 3 + kx], v);
            m = fmaxf(m, v);
          }
        s_p1[o][ly * 36 + lx] = m;
      }
    }
  }
  __syncthreads();

  // Phase C: conv2 (3x3, 16->32ch) + relu + sum over tile.
  // Thread task = 4 out-channels x (4x4 spatial); per-ic 6x6 patch in regs.
  float psum[8];
#pragma unroll
  for (int it = 0; it < 2; it++) {
    int task = tid + it * 256;
    int ocg = task >> 6, sp = task & 63;
    int sy = (sp >> 3) << 2, sx = (sp & 7) << 2;
    float acc[4][16];
#pragma unroll
    for (int a = 0; a < 4; a++)
#pragma unroll
      for (int q = 0; q < 16; q++) acc[a][q] = 0.f;

    for (int ic = 0; ic < 16; ic++) {
      float p[6][6];
#pragma unroll
      for (int i = 0; i < 6; i++) {
        const float* row = &s_p1[ic][(sy + i) * 36 + sx];
#pragma unroll
        for (int j = 0; j < 6; j++) p[i][j] = row[j];
      }
#pragma unroll
      for (int o4 = 0; o4 < 4; o4++) {
        const int oc = ocg * 4 + o4;
        const float* w = &s_w2[(oc * 16 + ic) * 9];
        float w00 = w[0], w01 = w[1], w02 = w[2];
        float w10 = w[3], w11 = w[4], w12 = w[5];
        float w20 = w[6], w21 = w[7], w22 = w[8];
#pragma unroll
        for (int y = 0; y < 4; y++)
#pragma unroll
          for (int x = 0; x < 4; x++) {
            float s = acc[o4][y * 4 + x];
            s = fmaf(p[y][x], w00, s);
            s = fmaf(p[y][x + 1], w01, s);
            s = fmaf(p[y][x + 2], w02, s);
            s = fmaf(p[y + 1][x], w10, s);
            s = fmaf(p[y + 1][x + 1], w11, s);
            s = fmaf(p[y + 1][x + 2], w12, s);
            s = fmaf(p[y + 2][x], w20, s);
            s = fmaf(p[y + 2][x + 1], w21, s);
            s = fmaf(p[y + 2][x + 2], w22, s);
            acc[o4][y * 4 + x] = s;
          }
      }
    }
#pragma unroll
    for (int o4 = 0; o4 < 4; o4++) {
      float bv = s_b2[ocg * 4 + o4];
      float s = 0.f;
#pragma unroll
      for (int q = 0; q < 16; q++) s += fmaxf(acc[o4][q] + bv, 0.f);
      psum[it * 4 + o4] = s;
    }
  }

  // Per-wave reduction: each wave has uniform ocg per 'it'.
  int lane = tid & 63;
#pragma unroll
  for (int v = 0; v < 8; v++) {
    float s = psum[v];
    for (int off = 32; off > 0; off >>= 1) s += __shfl_down(s, off, 64);
    if (lane == 0) {
      int it = v >> 2, o4 = v & 3;
      int ocg = (tid + it * 256) >> 6;
      part[(b * 16 + tile) * 32 + ocg * 4 + o4] = s;
    }
  }
}

// ============================================================================
// Stage 2a: reduce tile partials -> pooled mean (in LDS), then h0 GEMM (K=32).
// Also zero-initializes the LSTM cell state. One block per batch element.
// ============================================================================
__global__ __launch_bounds__(256) void k_pool_h0(
    const float* __restrict__ part, const float* __restrict__ feat_w,
    const float* __restrict__ feat_b, float* __restrict__ h0,
    float* __restrict__ cbuf)
{
  const int b = blockIdx.x, tid = threadIdx.x;
  __shared__ float pl[32];
  if (tid < 32) {
    float s = 0.f;
    for (int t = 0; t < 16; t++) s += part[(b * 16 + t) * 32 + tid];
    pl[tid] = s * (1.0f / 16384.0f);
  }
  __syncthreads();
  for (int j = tid; j < 512; j += 256) {
    float acc = feat_b[j];
    const float* w = feat_w + j * 32;
#pragma unroll
    for (int ic = 0; ic < 32; ic++) acc = fmaf(pl[ic], w[ic], acc);
    h0[b * 512 + j] = acc;
    cbuf[b * 512 + j] = 0.f;
  }
}

// ============================================================================
// Stage 2b: ctx = h0 @ ctx_w.T + ctx_b. One block per batch element.
// ============================================================================
__global__ __launch_bounds__(256) void k_ctx(
    const float* __restrict__ h0, const float* __restrict__ ctx_w,
    const float* __restrict__ ctx_b, float* __restrict__ ctx)
{
  const int b = blockIdx.x, tid = threadIdx.x;
  __shared__ float hs[512];
  for (int k = tid; k < 512; k += 256) hs[k] = h0[b * 512 + k];
  __syncthreads();
  for (int j = tid; j < 512; j += 256) {
    const float* w = ctx_w + (size_t)j * 512;
    float s0 = 0.f, s1 = 0.f, s2 = 0.f, s3 = 0.f;
    for (int k = 0; k < 512; k += 4) {
      float4 w4 = *(const float4*)(w + k);
      s0 = fmaf(hs[k], w4.x, s0);
      s1 = fmaf(hs[k + 1], w4.y, s1);
      s2 = fmaf(hs[k + 2], w4.z, s2);
      s3 = fmaf(hs[k + 3], w4.w, s3);
    }
    ctx[b * 512 + j] = ctx_b[j] + ((s0 + s1) + (s2 + s3));
  }
}

// ============================================================================
// Stage 3a: build LSTM input rows A[(t*64+b)][k] = tok_emb[tok][k] + ctx[b][k]
// ============================================================================
__global__ __launch_bounds__(128) void k_build_A(
    const float* __restrict__ tok_emb, const int* __restrict__ tgt,
    const float* __restrict__ ctx, float* __restrict__ A)
{
  const int r = blockIdx.x;
  const int t = r >> 6, b = r & 63;
  const int tok = (t == 0) ? 4096 : tgt[b * 50 + (t - 1)];
  const float4* e = (const float4*)(tok_emb + (size_t)tok * 512);
  const float4* c = (const float4*)(ctx + b * 512);
  float4* o = (float4*)(A + (size_t)r * 512);
  const int i = threadIdx.x;
  float4 ev = e[i], cv = c[i];
  o[i] = make_float4(ev.x + cv.x, ev.y + cv.y, ev.z + cv.z, ev.w + cv.w);
}

// ============================================================================
// Tiled fp32 GEMM: C(MxN) = A(Mx512) @ B(Nx512)^T + bias.
// 128x128 tile, 256 threads, 8x8 accumulators/thread, K-chunk 16.
// MODE 0: xgates (bias = b_ih + b_hh, row-major out, N=2048)
// MODE 1: head   (bias = head_b, out remapped (t*64+b,v) -> (b,t,v), N=4096)
// ============================================================================
template <int MODE>
__global__ __launch_bounds__(256) void k_gemm(
    const float* __restrict__ A, const float* __restrict__ B,
    const float* __restrict__ bias_a, const float* __restrict__ bias_b,
    float* __restrict__ C, int NB)
{
  __shared__ float As[16][132];
  __shared__ float Bs[16][132];
  const int tid = threadIdx.x;
  const int bx = blockIdx.x % NB, by = blockIdx.x / NB;
  const int tx = tid & 15, ty = tid >> 4;
  const float* Ab = A + (size_t)by * 128 * 512;
  const float* Bb = B + (size_t)bx * 128 * 512;

  float acc[8][8];
#pragma unroll
  for (int i = 0; i < 8; i++)
#pragma unroll
    for (int j = 0; j < 8; j++) acc[i][j] = 0.f;

  for (int kc = 0; kc < 512; kc += 16) {
#pragma unroll
    for (int i = 0; i < 2; i++) {
      int idx = tid + i * 256;
      int r = idx >> 2, k4 = (idx & 3) << 2;
      float4 av = *(const float4*)(Ab + (size_t)r * 512 + kc + k4);
      As[k4 + 0][r] = av.x; As[k4 + 1][r] = av.y;
      As[k4 + 2][r] = av.z; As[k4 + 3][r] = av.w;
      float4 bv = *(const float4*)(Bb + (size_t)r * 512 + kc + k4);
      Bs[k4 + 0][r] = bv.x; Bs[k4 + 1][r] = bv.y;
      Bs[k4 + 2][r] = bv.z; Bs[k4 + 3][r] = bv.w;
    }
    __syncthreads();
#pragma unroll
    for (int k = 0; k < 16; k++) {
      float4 a0 = *(const float4*)&As[k][ty * 8];
      float4 a1 = *(const float4*)&As[k][ty * 8 + 4];
      float4 b0 = *(const float4*)&Bs[k][tx * 8];
      float4 b1 = *(const float4*)&Bs[k][tx * 8 + 4];
      float av[8] = {a0.x, a0.y, a0.z, a0.w, a1.x, a1.y, a1.z, a1.w};
      float bv[8] = {b0.x, b0.y, b0.z, b0.w, b1.x, b1.y, b1.z, b1.w};
#pragma unroll
      for (int i = 0; i < 8; i++)
#pragma unroll
        for (int j = 0; j < 8; j++) acc[i][j] = fmaf(av[i], bv[j], acc[i][j]);
    }
    __syncthreads();
  }

  const int row0 = by * 128 + ty * 8, col0 = bx * 128 + tx * 8;
  float bias[8];
#pragma unroll
  for (int j = 0; j < 8; j++)
    bias[j] = (MODE == 0) ? (bias_a[col0 + j] + bias_b[col0 + j])
                          : bias_a[col0 + j];
#pragma unroll
  for (int i = 0; i < 8; i++) {
    int r = row0 + i;
    float* crow;
    if (MODE == 0) {
      crow = C + (size_t)r * 2048 + col0;
    } else {
      int t = r >> 6, bb = r & 63;
      crow = C + ((size_t)bb * 50 + t) * 4096 + col0;
    }
#pragma unroll
    for (int j = 0; j < 8; j++) crow[j] = acc[i][j] + bias[j];
  }
}

// ============================================================================
// Stage 4: one LSTM recurrence step.
// Grid 128 blocks x 256 thr; block owns 4 hidden indices (all 4 gates).
// Thread = (hidden dd, batch b). w_hh rows staged in LDS (broadcast reads);
// h_prev rows streamed from L1/L2.
// ============================================================================
__global__ __launch_bounds__(256) void k_lstm_step(
    const float* __restrict__ xg_t,    // (64,2048) precomputed input gates
    const float* __restrict__ w_hh,    // (2048,512)
    const float* __restrict__ h_prev,  // (64,512)
    float* __restrict__ h_out,         // (64,512)
    float* __restrict__ c_buf)         // (64,512) in/out
{
  __shared__ float s_w[4][4][512];  // [dd_i][gate][k]
  const int tid = threadIdx.x;
  const int dd0 = blockIdx.x * 4;

  for (int idx = tid; idx < 16 * 128; idx += 256) {
    int row_i = idx >> 7;
    int k4 = (idx & 127) << 2;
    int dd_i = row_i >> 2, g = row_i & 3;
    float4 v = *(const float4*)(w_hh + (size_t)(g * 512 + dd0 + dd_i) * 512 + k4);
    *(float4*)&s_w[dd_i][g][k4] = v;
  }
  __syncthreads();

  const int b = tid & 63;
  const int dd_i = tid >> 6;
  const int dd = dd0 + dd_i;

  float acc0 = xg_t[b * 2048 + 0 * 512 + dd];
  float acc1 = xg_t[b * 2048 + 1 * 512 + dd];
  float acc2 = xg_t[b * 2048 + 2 * 512 + dd];
  float acc3 = xg_t[b * 2048 + 3 * 512 + dd];

  const float* hr = h_prev + b * 512;
#pragma unroll 8
  for (int k = 0; k < 512; k += 4) {
    float4 h4 = *(const float4*)(hr + k);
    float4 w0 = *(const float4*)&s_w[dd_i][0][k];
    float4 w1 = *(const float4*)&s_w[dd_i][1][k];
    float4 w2 = *(const float4*)&s_w[dd_i][2][k];
    float4 w3 = *(const float4*)&s_w[dd_i][3][k];
    acc0 = fmaf(h4.x, w0.x, fmaf(h4.y, w0.y, fmaf(h4.z, w0.z, fmaf(h4.w, w0.w, acc0))));
    acc1 = fmaf(h4.x, w1.x, fmaf(h4.y, w1.y, fmaf(h4.z, w1.z, fmaf(h4.w, w1.w, acc1))));
    acc2 = fmaf(h4.x, w2.x, fmaf(h4.y, w2.y, fmaf(h4.z, w2.z, fmaf(h4.w, w2.w, acc2))));
    acc3 = fmaf(h4.x, w3.x, fmaf(h4.y, w3.y, fmaf(h4.z, w3.z, fmaf(h4.w, w3.w, acc3))));
  }

  float ig = 1.f / (1.f + expf(-acc0));
  float fg = 1.f / (1.f + expf(-acc1));
  float gg = tanhf(acc2);
  float og = 1.f / (1.f + expf(-acc3));
  float c = fmaf(fg, c_buf[b * 512 + dd], ig * gg);
  float h = og * tanhf(c);
  c_buf[b * 512 + dd] = c;
  h_out[b * 512 + dd] = h;
}

// ============================================================================
extern "C" void kernel_launch(void* const* d_in, const int* in_sizes, int n_in,
                              void* d_out, int out_size, void* d_ws,
                              size_t ws_size, hipStream_t stream) {
  const float* mask   = (const float*)d_in[0];
  const int*   tgt    = (const int*)d_in[1];
  const float* w1     = (const float*)d_in[2];
  const float* b1     = (const float*)d_in[3];
  const float* w2     = (const float*)d_in[4];
  const float* b2     = (const float*)d_in[5];
  const float* feat_w = (const float*)d_in[6];
  const float* feat_b = (const float*)d_in[7];
  const float* ctx_w  = (const float*)d_in[8];
  const float* ctx_b  = (const float*)d_in[9];
  const float* temb   = (const float*)d_in[10];
  const float* w_ih   = (const float*)d_in[11];
  const float* w_hh   = (const float*)d_in[12];
  const float* b_ih   = (const float*)d_in[13];
  const float* b_hh   = (const float*)d_in[14];
  const float* head_w = (const float*)d_in[15];
  const float* head_b = (const float*)d_in[16];

  float* ws   = (float*)d_ws;
  float* part = ws;                 // 64*16*32      = 32768
  float* h0   = part + 32768;       // 64*512        = 32768
  float* cbuf = h0 + 32768;         // 64*512
  float* ctx  = cbuf + 32768;       // 64*512
  float* A    = ctx + 32768;        // 3200*512      = 1638400
  float* xg   = A + 1638400;        // 3200*2048     = 6553600
  float* hall = xg + 6553600;       // 3200*512      = 1638400
  float* out  = (float*)d_out;      // 64*50*4096

  k_conv<<<1024, 256, 0, stream>>>(mask, w1, b1, w2, b2, part);
  k_pool_h0<<<64, 256, 0, stream>>>(part, feat_w, feat_b, h0, cbuf);
  k_ctx<<<64, 256, 0, stream>>>(h0, ctx_w, ctx_b, ctx);
  k_build_A<<<3200, 128, 0, stream>>>(temb, tgt, ctx, A);
  k_gemm<0><<<25 * 16, 256, 0, stream>>>(A, w_ih, b_ih, b_hh, xg, 16);
  for (int t = 0; t < 50; t++) {
    const float* hp = (t == 0) ? h0 : hall + (size_t)(t - 1) * 32768;
    k_lstm_step<<<128, 256, 0, stream>>>(xg + (size_t)t * 131072, w_hh, hp,
                                         hall + (size_t)t * 32768, cbuf);
  }
  k_gemm<1><<<25 * 32, 256, 0, stream>>>(hall, head_w, head_b, nullptr, out, 32);
}

// Round 2
// 1426.446 us; speedup vs baseline: 1.1885x; 1.1885x over previous
//
#include <hip/hip_runtime.h>
#include <cmath>

typedef __attribute__((ext_vector_type(8))) short bf16x8;
typedef __attribute__((ext_vector_type(4))) float f32x4;

__device__ __forceinline__ unsigned short f2b(float x) {
  unsigned u = __builtin_bit_cast(unsigned, x);
  u += 0x7fffu + ((u >> 16) & 1u);
  return (unsigned short)(u >> 16);
}

__device__ __forceinline__ void gload16(const void* g, void* l) {
  __builtin_amdgcn_global_load_lds(
      (const __attribute__((address_space(1))) void*)g,
      (__attribute__((address_space(3))) void*)l, 16, 0, 0);
}

// ============================================================================
// Stage 1: fused conv1 + relu + maxpool2x2 + conv2 + relu + spatial-sum
// 512 threads (2 waves/SIMD vs round-1's 1 — latency hiding was the limiter).
// ============================================================================
__global__ __launch_bounds__(512) void k_conv(
    const float* __restrict__ mask, const float* __restrict__ w1,
    const float* __restrict__ b1, const float* __restrict__ w2,
    const float* __restrict__ b2, float* __restrict__ part)
{
  __shared__ float s_p1[16][34 * 36];
  __shared__ float s_w1[144];
  __shared__ float s_b1[16];
  __shared__ float s_w2[4608];
  __shared__ float s_b2[32];

  const int tid = threadIdx.x;
  const int b = blockIdx.x >> 4;
  const int tile = blockIdx.x & 15;
  const int py0 = (tile >> 2) * 32, px0 = (tile & 3) * 32;
  const float* mb = mask + (size_t)b * 65536;

  for (int i = tid; i < 144; i += 512) s_w1[i] = w1[i];
  for (int i = tid; i < 4608; i += 512) s_w2[i] = w2[i];
  if (tid < 16) s_b1[tid] = b1[tid];
  if (tid < 32) s_b2[tid] = b2[tid];
  __syncthreads();

  // conv1 + relu + 2x2 maxpool into s_p1 (34x34 incl. halo), relu folded in.
  for (int idx = tid; idx < 34 * 34; idx += 512) {
    int ly = idx / 34, lx = idx % 34;
    int py = py0 - 1 + ly, px = px0 - 1 + lx;
    if (py < 0 || py >= 128 || px < 0 || px >= 128) {
      for (int o = 0; o < 16; o++) s_p1[o][ly * 36 + lx] = 0.f;
    } else {
      float patch[4][4];
      int gy0 = 2 * py - 1, gx0 = 2 * px - 1;
#pragma unroll
      for (int i = 0; i < 4; i++) {
        int gy = gy0 + i;
        bool yok = (gy >= 0 && gy < 256);
#pragma unroll
        for (int j = 0; j < 4; j++) {
          int gx = gx0 + j;
          patch[i][j] = (yok && gx >= 0 && gx < 256) ? mb[gy * 256 + gx] : 0.f;
        }
      }
      for (int o = 0; o < 16; o++) {
        float m = 0.f;
#pragma unroll
        for (int dy = 0; dy < 2; dy++)
#pragma unroll
          for (int dx = 0; dx < 2; dx++) {
            float v = s_b1[o];
#pragma unroll
            for (int ky = 0; ky < 3; ky++)
#pragma unroll
              for (int kx = 0; kx < 3; kx++)
                v = fmaf(patch[dy + ky][dx + kx], s_w1[o * 9 + ky * 3 + kx], v);
            m = fmaxf(m, v);
          }
        s_p1[o][ly * 36 + lx] = m;
      }
    }
  }
  __syncthreads();

  // conv2 (3x3, 16->32ch) + relu + tile-sum. Thread = 4 oc x (4x4 spatial).
  const int ocg = tid >> 6;          // 0..7 (uniform per wave)
  const int sp = tid & 63;
  const int sy = (sp >> 3) << 2, sx = (sp & 7) << 2;
  float acc[4][16];
#pragma unroll
  for (int a = 0; a < 4; a++)
#pragma unroll
    for (int q = 0; q < 16; q++) acc[a][q] = 0.f;

  for (int ic = 0; ic < 16; ic++) {
    float p[6][6];
#pragma unroll
    for (int i = 0; i < 6; i++) {
      const float* row = &s_p1[ic][(sy + i) * 36 + sx];
#pragma unroll
      for (int j = 0; j < 6; j++) p[i][j] = row[j];
    }
#pragma unroll
    for (int o4 = 0; o4 < 4; o4++) {
      const int oc = ocg * 4 + o4;
      const float* w = &s_w2[(oc * 16 + ic) * 9];
      float w00 = w[0], w01 = w[1], w02 = w[2];
      float w10 = w[3], w11 = w[4], w12 = w[5];
      float w20 = w[6], w21 = w[7], w22 = w[8];
#pragma unroll
      for (int y = 0; y < 4; y++)
#pragma unroll
        for (int x = 0; x < 4; x++) {
          float s = acc[o4][y * 4 + x];
          s = fmaf(p[y][x], w00, s);
          s = fmaf(p[y][x + 1], w01, s);
          s = fmaf(p[y][x + 2], w02, s);
          s = fmaf(p[y + 1][x], w10, s);
          s = fmaf(p[y + 1][x + 1], w11, s);
          s = fmaf(p[y + 1][x + 2], w12, s);
          s = fmaf(p[y + 2][x], w20, s);
          s = fmaf(p[y + 2][x + 1], w21, s);
          s = fmaf(p[y + 2][x + 2], w22, s);
          acc[o4][y * 4 + x] = s;
        }
    }
  }

  const int lane = tid & 63;
#pragma unroll
  for (int o4 = 0; o4 < 4; o4++) {
    float bv = s_b2[ocg * 4 + o4];
    float s = 0.f;
#pragma unroll
    for (int q = 0; q < 16; q++) s += fmaxf(acc[o4][q] + bv, 0.f);
    for (int off = 32; off > 0; off >>= 1) s += __shfl_down(s, off, 64);
    if (lane == 0) part[(b * 16 + tile) * 32 + ocg * 4 + o4] = s;
  }
}

// ============================================================================
// Stage 2a: tile partials -> pooled mean -> h0 GEMM (K=32); zero cell state.
// ============================================================================
__global__ __launch_bounds__(256) void k_pool_h0(
    const float* __restrict__ part, const float* __restrict__ feat_w,
    const float* __restrict__ feat_b, float* __restrict__ h0,
    float* __restrict__ cbuf)
{
  const int b = blockIdx.x, tid = threadIdx.x;
  __shared__ float pl[32];
  if (tid < 32) {
    float s = 0.f;
    for (int t = 0; t < 16; t++) s += part[(b * 16 + t) * 32 + tid];
    pl[tid] = s * (1.0f / 16384.0f);
  }
  __syncthreads();
  for (int j = tid; j < 512; j += 256) {
    float acc = feat_b[j];
    const float* w = feat_w + j * 32;
#pragma unroll
    for (int ic = 0; ic < 32; ic++) acc = fmaf(pl[ic], w[ic], acc);
    h0[b * 512 + j] = acc;
    cbuf[b * 512 + j] = 0.f;
  }
}

// ============================================================================
// Stage 2b: ctx = h0 @ ctx_w.T + ctx_b.
// ============================================================================
__global__ __launch_bounds__(256) void k_ctx(
    const float* __restrict__ h0, const float* __restrict__ ctx_w,
    const float* __restrict__ ctx_b, float* __restrict__ ctx)
{
  const int b = blockIdx.x, tid = threadIdx.x;
  __shared__ float hs[512];
  for (int k = tid; k < 512; k += 256) hs[k] = h0[b * 512 + k];
  __syncthreads();
  for (int j = tid; j < 512; j += 256) {
    const float* w = ctx_w + (size_t)j * 512;
    float s0 = 0.f, s1 = 0.f, s2 = 0.f, s3 = 0.f;
    for (int k = 0; k < 512; k += 4) {
      float4 w4 = *(const float4*)(w + k);
      s0 = fmaf(hs[k], w4.x, s0);
      s1 = fmaf(hs[k + 1], w4.y, s1);
      s2 = fmaf(hs[k + 2], w4.z, s2);
      s3 = fmaf(hs[k + 3], w4.w, s3);
    }
    ctx[b * 512 + j] = ctx_b[j] + ((s0 + s1) + (s2 + s3));
  }
}

// ============================================================================
// fp32 -> bf16 (RNE) conversion, 4 elems/thread.
// ============================================================================
__global__ __launch_bounds__(256) void k_f2b(
    const float* __restrict__ in, unsigned short* __restrict__ out, int n)
{
  int i = (blockIdx.x * 256 + threadIdx.x) * 4;
  if (i < n) {
    float4 v = *(const float4*)(in + i);
    unsigned lo = (unsigned)f2b(v.x) | ((unsigned)f2b(v.y) << 16);
    unsigned hi = (unsigned)f2b(v.z) | ((unsigned)f2b(v.w) << 16);
    *(uint2*)(out + i) = make_uint2(lo, hi);
  }
}

// ============================================================================
// Stage 3a: A[(t*64+b)][k] = bf16(tok_emb[tok][k] + ctx[b][k])
// ============================================================================
__global__ __launch_bounds__(128) void k_build_A(
    const float* __restrict__ tok_emb, const int* __restrict__ tgt,
    const float* __restrict__ ctx, unsigned short* __restrict__ A)
{
  const int r = blockIdx.x;
  const int t = r >> 6, b = r & 63;
  const int tok = (t == 0) ? 4096 : tgt[b * 50 + (t - 1)];
  const int i = threadIdx.x * 4;
  float4 ev = *(const float4*)(tok_emb + (size_t)tok * 512 + i);
  float4 cv = *(const float4*)(ctx + b * 512 + i);
  unsigned lo = (unsigned)f2b(ev.x + cv.x) | ((unsigned)f2b(ev.y + cv.y) << 16);
  unsigned hi = (unsigned)f2b(ev.z + cv.z) | ((unsigned)f2b(ev.w + cv.w) << 16);
  *(uint2*)(A + (size_t)r * 512 + i) = make_uint2(lo, hi);
}

// ============================================================================
// bf16 MFMA GEMM (m97 structure): C(Mx N) = A(Mx512) @ B(Nx512)^T + bias.
// 128x128 tile, BK=32, 4 waves, global_load_lds(16B), 16x16x32 bf16 MFMA.
// MODE 0: xgates (bias b_ih+b_hh, C row-major (t*64+b, 2048))
// MODE 1: head   (bias head_b, C remapped (t*64+b, v) -> (b*50+t, v))
// ============================================================================
template <int MODE>
__global__ __launch_bounds__(256) void k_gemm_mfma(
    const unsigned short* __restrict__ A, const unsigned short* __restrict__ B,
    const float* __restrict__ bias_a, const float* __restrict__ bias_b,
    float* __restrict__ C, int NB)
{
  __shared__ unsigned short sA[128 * 32];
  __shared__ unsigned short sB[128 * 32];
  const int tid = threadIdx.x;
  const int bx = blockIdx.x % NB, by = blockIdx.x / NB;
  const int lane = tid & 63, wv = tid >> 6;
  const int wr = wv >> 1, wc = wv & 1;  // wave -> 64x64 quadrant
  const unsigned short* Ab = A + (size_t)by * 128 * 512;
  const unsigned short* Bb = B + (size_t)bx * 128 * 512;

  f32x4 acc[4][4];
#pragma unroll
  for (int m = 0; m < 4; m++)
#pragma unroll
    for (int n = 0; n < 4; n++) acc[m][n] = (f32x4){0.f, 0.f, 0.f, 0.f};

  // staging chunks: idx in [0,512), row = idx>>2, 8-elem group c = idx&3
  const int r0 = tid >> 2, c0 = (tid & 3) * 8;
  const int idx1 = tid + 256;
  const int r1 = idx1 >> 2, c1 = (idx1 & 3) * 8;
  unsigned short* lA0 = sA + (size_t)wv * 512;           // wv*1024 bytes
  unsigned short* lA1 = sA + 2048 + (size_t)wv * 512;    // +4096 bytes
  unsigned short* lB0 = sB + (size_t)wv * 512;
  unsigned short* lB1 = sB + 2048 + (size_t)wv * 512;

  const int frow = lane & 15;
  const int foff = (lane >> 4) * 8;

  for (int kc = 0; kc < 512; kc += 32) {
    gload16(Ab + (size_t)r0 * 512 + kc + c0, lA0);
    gload16(Ab + (size_t)r1 * 512 + kc + c1, lA1);
    gload16(Bb + (size_t)r0 * 512 + kc + c0, lB0);
    gload16(Bb + (size_t)r1 * 512 + kc + c1, lB1);
    __syncthreads();

    bf16x8 af[4], bfr[4];
#pragma unroll
    for (int m = 0; m < 4; m++)
      af[m] = *(const bf16x8*)(sA + (wr * 64 + m * 16 + frow) * 32 + foff);
#pragma unroll
    for (int n = 0; n < 4; n++)
      bfr[n] = *(const bf16x8*)(sB + (wc * 64 + n * 16 + frow) * 32 + foff);
#pragma unroll
    for (int m = 0; m < 4; m++)
#pragma unroll
      for (int n = 0; n < 4; n++)
        acc[m][n] = __builtin_amdgcn_mfma_f32_16x16x32_bf16(
            af[m], bfr[n], acc[m][n], 0, 0, 0);
    __syncthreads();
  }

  // C/D layout (m91-verified): col = lane&15, row = (lane>>4)*4 + j
#pragma unroll
  for (int n = 0; n < 4; n++) {
    const int gc = bx * 128 + wc * 64 + n * 16 + (lane & 15);
    const float bv = (MODE == 0) ? (bias_a[gc] + bias_b[gc]) : bias_a[gc];
#pragma unroll
    for (int m = 0; m < 4; m++) {
      const int rb = by * 128 + wr * 64 + m * 16 + (lane >> 4) * 4;
#pragma unroll
      for (int j = 0; j < 4; j++) {
        const int r = rb + j;
        float v = acc[m][n][j] + bv;
        if (MODE == 0) {
          C[(size_t)r * 2048 + gc] = v;
        } else {
          int t = r >> 6, bb = r & 63;
          C[((size_t)bb * 50 + t) * 4096 + gc] = v;
        }
      }
    }
  }
}

// ============================================================================
// Stage 4: one LSTM step (fp32 recurrence). Also emits bf16 h for head GEMM.
// ============================================================================
__global__ __launch_bounds__(256) void k_lstm_step(
    const float* __restrict__ xg_t,    // (64,2048)
    const float* __restrict__ w_hh,    // (2048,512)
    const float* __restrict__ h_prev,  // (64,512) fp32
    float* __restrict__ h_out,         // (64,512) fp32
    unsigned short* __restrict__ hb,   // (64,512) bf16 for head GEMM
    float* __restrict__ c_buf)         // (64,512) in/out
{
  __shared__ float s_w[4][4][512];  // [dd_i][gate][k]
  const int tid = threadIdx.x;
  const int dd0 = blockIdx.x * 4;

  for (int idx = tid; idx < 16 * 128; idx += 256) {
    int row_i = idx >> 7;
    int k4 = (idx & 127) << 2;
    int dd_i = row_i >> 2, g = row_i & 3;
    float4 v = *(const float4*)(w_hh + (size_t)(g * 512 + dd0 + dd_i) * 512 + k4);
    *(float4*)&s_w[dd_i][g][k4] = v;
  }
  __syncthreads();

  const int b = tid & 63;
  const int dd_i = tid >> 6;
  const int dd = dd0 + dd_i;

  float acc0 = xg_t[b * 2048 + 0 * 512 + dd];
  float acc1 = xg_t[b * 2048 + 1 * 512 + dd];
  float acc2 = xg_t[b * 2048 + 2 * 512 + dd];
  float acc3 = xg_t[b * 2048 + 3 * 512 + dd];

  const float* hr = h_prev + b * 512;
#pragma unroll 8
  for (int k = 0; k < 512; k += 4) {
    float4 h4 = *(const float4*)(hr + k);
    float4 w0 = *(const float4*)&s_w[dd_i][0][k];
    float4 w1 = *(const float4*)&s_w[dd_i][1][k];
    float4 w2 = *(const float4*)&s_w[dd_i][2][k];
    float4 w3 = *(const float4*)&s_w[dd_i][3][k];
    acc0 = fmaf(h4.x, w0.x, fmaf(h4.y, w0.y, fmaf(h4.z, w0.z, fmaf(h4.w, w0.w, acc0))));
    acc1 = fmaf(h4.x, w1.x, fmaf(h4.y, w1.y, fmaf(h4.z, w1.z, fmaf(h4.w, w1.w, acc1))));
    acc2 = fmaf(h4.x, w2.x, fmaf(h4.y, w2.y, fmaf(h4.z, w2.z, fmaf(h4.w, w2.w, acc2))));
    acc3 = fmaf(h4.x, w3.x, fmaf(h4.y, w3.y, fmaf(h4.z, w3.z, fmaf(h4.w, w3.w, acc3))));
  }

  float ig = 1.f / (1.f + expf(-acc0));
  float fg = 1.f / (1.f + expf(-acc1));
  float gg = tanhf(acc2);
  float og = 1.f / (1.f + expf(-acc3));
  float c = fmaf(fg, c_buf[b * 512 + dd], ig * gg);
  float h = og * tanhf(c);
  c_buf[b * 512 + dd] = c;
  h_out[b * 512 + dd] = h;
  hb[b * 512 + dd] = f2b(h);
}

// ============================================================================
extern "C" void kernel_launch(void* const* d_in, const int* in_sizes, int n_in,
                              void* d_out, int out_size, void* d_ws,
                              size_t ws_size, hipStream_t stream) {
  const float* mask   = (const float*)d_in[0];
  const int*   tgt    = (const int*)d_in[1];
  const float* w1     = (const float*)d_in[2];
  const float* b1     = (const float*)d_in[3];
  const float* w2     = (const float*)d_in[4];
  const float* b2     = (const float*)d_in[5];
  const float* feat_w = (const float*)d_in[6];
  const float* feat_b = (const float*)d_in[7];
  const float* ctx_w  = (const float*)d_in[8];
  const float* ctx_b  = (const float*)d_in[9];
  const float* temb   = (const float*)d_in[10];
  const float* w_ih   = (const float*)d_in[11];
  const float* w_hh   = (const float*)d_in[12];
  const float* b_ih   = (const float*)d_in[13];
  const float* b_hh   = (const float*)d_in[14];
  const float* head_w = (const float*)d_in[15];
  const float* head_b = (const float*)d_in[16];

  float* ws = (float*)d_ws;
  // float-unit offsets (total 9,961,472 floats = 39.85 MB, same as round 1)
  float* part  = ws;                        // 32768
  float* h0    = ws + 32768;                // 32768
  float* cbuf  = ws + 65536;                // 32768
  float* ctx   = ws + 98304;                // 32768
  float* hp0   = ws + 131072;               // 32768 (h ping)
  float* hp1   = ws + 163840;               // 32768 (h pong)
  unsigned short* Ab16  = (unsigned short*)(ws + 196608);   // 3200*512 bf16
  unsigned short* wihb  = (unsigned short*)(ws + 1015808);  // 2048*512 bf16
  unsigned short* hwb   = (unsigned short*)(ws + 1540096);  // 4096*512 bf16
  float* xg    = ws + 2588672;              // 3200*2048 fp32
  unsigned short* hallb = (unsigned short*)(ws + 9142272);  // 3200*512 bf16
  float* out   = (float*)d_out;             // (64,50,4096)

  k_conv<<<1024, 512, 0, stream>>>(mask, w1, b1, w2, b2, part);
  k_f2b<<<1024, 256, 0, stream>>>(w_ih, wihb, 1048576);
  k_f2b<<<2048, 256, 0, stream>>>(head_w, hwb, 2097152);
  k_pool_h0<<<64, 256, 0, stream>>>(part, feat_w, feat_b, h0, cbuf);
  k_ctx<<<64, 256, 0, stream>>>(h0, ctx_w, ctx_b, ctx);
  k_build_A<<<3200, 128, 0, stream>>>(temb, tgt, ctx, Ab16);
  k_gemm_mfma<0><<<25 * 16, 256, 0, stream>>>(Ab16, wihb, b_ih, b_hh, xg, 16);
  for (int t = 0; t < 50; t++) {
    const float* hp = (t == 0) ? h0 : ((t & 1) ? hp0 : hp1);
    float* ho = (t & 1) ? hp1 : hp0;
    k_lstm_step<<<128, 256, 0, stream>>>(xg + (size_t)t * 131072, w_hh, hp,
                                         ho, hallb + (size_t)t * 32768, cbuf);
  }
  k_gemm_mfma<1><<<25 * 32, 256, 0, stream>>>(hallb, hwb, head_b, nullptr, out, 32);
}